// Round 7
// baseline (182.727 us; speedup 1.0000x reference)
//
#include <hip/hip_runtime.h>
#include <hip/hip_cooperative_groups.h>
#include <stdint.h>
#include <math.h>

namespace cg = cooperative_groups;

#define NCLS 81
#define NFG  80
#define NPI  1024
#define NIMG 8
#define DETS 100
#define SCORE_T 0.05f
#define NMS_T   0.5f
#define NCAND   (NFG * DETS)   // 8000
#define CAND_CAP 2048
#define FASTN 256              // block bitmask-NMS path limit
#define ROWS 64                // rows per softmax block
#define GRID_BLOCKS 512        // 2 blocks/CU guaranteed co-resident

static constexpr float BBOX_CLIP = 4.1351665567423557f; // log(1000/16)

struct ShP1 {
    float tile[ROWS * NCLS];
    float mx[ROWS], dn[ROWS];
};
struct ShP2 {
    float box[NPI][4];                         // 16KB (by proposal id)
    unsigned long long key[NPI];               // 8KB
    int keep[NPI];                             // 4KB
    float sbox[FASTN][4];                      // 4KB
    float sarea[FASTN];                        // 1KB
    unsigned long long mask[FASTN][FASTN/64];  // 8KB
    unsigned long long keepw[FASTN/64];
    unsigned wpre[4];
};
struct ShP3 {
    unsigned hist[4096];                       // 16KB
    unsigned long long cand[CAND_CAP];         // 16KB
    int cnts[NFG];
    unsigned wtot[4];
    int B1, B2, Nc;
    unsigned Ab1, Ab2;
};
union ShU { ShP1 p1; ShP2 p2; ShP3 p3; };

// ---- 256-thread suffix radix-select: bucket B with above(B) < K <= above(B)+cnt(B)
__device__ __forceinline__ void suffix_select256(
    unsigned* hist, unsigned* wtot, int K, int* outB, unsigned* outAbove)
{
    int t = threadIdx.x, lane = t & 63, w = t >> 6;
    unsigned loc[16]; unsigned ps = 0;
    #pragma unroll
    for (int j = 0; j < 16; ++j) { loc[j] = hist[t * 16 + j]; ps += loc[j]; }
    unsigned v = ps;
    #pragma unroll
    for (int off = 1; off < 64; off <<= 1) {
        unsigned u = __shfl_down(v, off, 64);
        v += (lane + off < 64) ? u : 0u;
    }
    if (lane == 0) wtot[w] = v;
    __syncthreads();
    unsigned woff = 0;
    for (int w2 = w + 1; w2 < 4; ++w2) woff += wtot[w2];
    unsigned base = v + woff - ps;     // strictly-after threads' totals
    unsigned suf = 0;
    #pragma unroll
    for (int j = 15; j >= 0; --j) {
        unsigned A = base + suf;       // count strictly above bucket t*16+j
        if ((int)A < K && (int)(A + loc[j]) >= K) { *outB = t * 16 + j; *outAbove = A; }
        suf += loc[j];
    }
    __syncthreads();
}

__global__ __launch_bounds__(256, 2) void fpn_fused(
    const float* __restrict__ logits, const float* __restrict__ boxreg,
    const float* __restrict__ props, const int* __restrict__ hptr,
    const int* __restrict__ wptr, float* __restrict__ probT,
    int* __restrict__ gcnt, float* __restrict__ escore,
    unsigned* __restrict__ ekey, float* __restrict__ ebox,
    float* __restrict__ out, int M)
{
    cg::grid_group grid = cg::this_grid();
    __shared__ ShU sh;
    __shared__ int cnt;
    int t = threadIdx.x;
    int bid = blockIdx.x;

    // ============ Phase 1: softmax -> transposed prob (blocks 0..127) ============
    if (bid < M / ROWS) {
        int rbase = bid * ROWS;
        for (int idx = t; idx < ROWS * NCLS; idx += 256)
            sh.p1.tile[idx] = logits[(size_t)rbase * NCLS + idx];
        __syncthreads();
        if (t < ROWS) {
            const float* r = sh.p1.tile + t * NCLS;
            float m = r[0];
            #pragma unroll
            for (int j = 1; j < NCLS; ++j) m = fmaxf(m, r[j]);
            float s = 0.f;
            #pragma unroll
            for (int j = 0; j < NCLS; ++j) s += expf(r[j] - m);
            sh.p1.mx[t] = m; sh.p1.dn[t] = s;
        }
        __syncthreads();
        for (int o = t; o < ROWS * NFG; o += 256) {
            int r = o & 63;
            int c = o >> 6;
            float v = expf(sh.p1.tile[r * NCLS + (c + 1)] - sh.p1.mx[r]) / sh.p1.dn[r];
            probT[(size_t)c * M + rbase + r] = v;
        }
    }
    grid.sync();

    // ============ Phase 2: per-(image,class) NMS, pid-strided over 640 ============
    for (int pid = bid; pid < NIMG * NFG; pid += GRID_BLOCKS) {
        int img = pid / NFG;
        int c   = pid % NFG;
        int cls = c + 1;
        float W1 = (float)(*wptr - 1);
        float H1 = (float)(*hptr - 1);

        if (t == 0) cnt = 0;
        for (int i = t; i < NPI; i += 256) sh.p2.key[i] = 0ULL;
        __syncthreads();

        {
            const float4 pv = *(const float4*)(probT + (size_t)c * M + img * NPI + 4 * t);
            float pr[4] = {pv.x, pv.y, pv.z, pv.w};
            #pragma unroll
            for (int j = 0; j < 4; ++j) {
                if (pr[j] > SCORE_T) {
                    int m = 4 * t + j;
                    int g = img * NPI + m;
                    const float4 pb = *(const float4*)(props + (size_t)g * 4);
                    float x1 = pb.x, y1 = pb.y, x2 = pb.z, y2 = pb.w;
                    float w  = x2 - x1 + 1.0f, h = y2 - y1 + 1.0f;
                    float cx = x1 + 0.5f * w,  cy = y1 + 0.5f * h;
                    const float4 rc = *(const float4*)(boxreg + (size_t)g * (4 * NCLS) + 4 * cls);
                    float dx = rc.x / 10.0f, dy = rc.y / 10.0f;
                    float dw = fminf(rc.z / 5.0f, BBOX_CLIP);
                    float dh = fminf(rc.w / 5.0f, BBOX_CLIP);
                    float pcx = dx * w + cx, pcy = dy * h + cy;
                    float pw = expf(dw) * w, ph = expf(dh) * h;
                    float bx1 = pcx - 0.5f * pw;
                    float by1 = pcy - 0.5f * ph;
                    float bx2 = pcx + 0.5f * pw - 1.0f;
                    float by2 = pcy + 0.5f * ph - 1.0f;
                    bx1 = fminf(fmaxf(bx1, 0.f), W1);
                    bx2 = fminf(fmaxf(bx2, 0.f), W1);
                    by1 = fminf(fmaxf(by1, 0.f), H1);
                    by2 = fminf(fmaxf(by2, 0.f), H1);
                    sh.p2.box[m][0] = bx1; sh.p2.box[m][1] = by1;
                    sh.p2.box[m][2] = bx2; sh.p2.box[m][3] = by2;
                    int p = atomicAdd(&cnt, 1);
                    unsigned fb = __float_as_uint(pr[j]);
                    sh.p2.key[p] = ((unsigned long long)fb << 32) | (unsigned)(NPI - 1 - m);
                }
            }
        }
        __syncthreads();
        int n = cnt;

        if (n <= 64) {
            // ---- wave fast path ----
            if (t < 64) {
                int lane = t;
                unsigned long long k = (lane < n) ? sh.p2.key[lane] : 0ULL;
                #pragma unroll
                for (int kk = 2; kk <= 64; kk <<= 1) {
                    #pragma unroll
                    for (int j = kk >> 1; j > 0; j >>= 1) {
                        unsigned long long o = __shfl_xor(k, j, 64);
                        bool up = ((lane & kk) == 0);
                        bool lower = ((lane & j) == 0);
                        bool take_max = (up == lower);
                        k = take_max ? (k > o ? k : o) : (k < o ? k : o);
                    }
                }
                bool valid = (lane < n);
                float bx1 = 0.f, by1 = 0.f, bx2 = 0.f, by2 = 0.f, area = 0.f;
                if (valid) {
                    int mi = NPI - 1 - (int)(k & 0xFFFFFFFFu);
                    bx1 = sh.p2.box[mi][0]; by1 = sh.p2.box[mi][1];
                    bx2 = sh.p2.box[mi][2]; by2 = sh.p2.box[mi][3];
                    area = (bx2 - bx1 + 1.f) * (by2 - by1 + 1.f);
                }
                unsigned long long sup = 0ULL;
                for (int i = 0; i < n; ++i) {
                    bool alive = !((sup >> i) & 1ULL);
                    float ax1 = __shfl(bx1, i, 64), ay1 = __shfl(by1, i, 64);
                    float ax2 = __shfl(bx2, i, 64), ay2 = __shfl(by2, i, 64);
                    float aarea = __shfl(area, i, 64);
                    bool s = false;
                    if (alive && valid && lane > i) {
                        float xx1 = fmaxf(ax1, bx1), yy1 = fmaxf(ay1, by1);
                        float xx2 = fminf(ax2, bx2), yy2 = fminf(ay2, by2);
                        float iw = fmaxf(xx2 - xx1 + 1.f, 0.f);
                        float ih = fmaxf(yy2 - yy1 + 1.f, 0.f);
                        float inter = iw * ih;
                        float iou = inter / (aarea + area - inter);
                        s = iou > NMS_T;
                    }
                    sup |= __ballot(s);
                }
                bool kept = valid && !((sup >> lane) & 1ULL);
                unsigned long long keptm = __ballot(kept);
                int rank = __popcll(keptm & ((1ULL << lane) - 1ULL));
                if (kept && rank < DETS) {
                    int slot = pid * DETS + rank;
                    escore[slot] = __uint_as_float((unsigned)(k >> 32));
                    ekey[slot] = (unsigned)(c * NPI + lane);
                    ebox[slot * 4 + 0] = bx1;
                    ebox[slot * 4 + 1] = by1;
                    ebox[slot * 4 + 2] = bx2;
                    ebox[slot * 4 + 3] = by2;
                }
                if (lane == 0) {
                    int tot = __popcll(keptm);
                    gcnt[pid] = tot < DETS ? tot : DETS;
                }
            }
        } else {
            // ---- block paths ----
            int P = 2;
            while (P < n) P <<= 1;
            for (int k = 2; k <= P; k <<= 1) {
                for (int j = k >> 1; j > 0; j >>= 1) {
                    for (int i = t; i < P; i += 256) {
                        int ixj = i ^ j;
                        if (ixj > i) {
                            unsigned long long a = sh.p2.key[i], b = sh.p2.key[ixj];
                            bool up = (i & k) == 0;
                            if (up ? (a < b) : (a > b)) { sh.p2.key[i] = b; sh.p2.key[ixj] = a; }
                        }
                    }
                    __syncthreads();
                }
            }

            for (int i = t; i < NPI; i += 256) sh.p2.keep[i] = 0;
            __syncthreads();

            if (n <= FASTN) {
                for (int i = t; i < n; i += 256) {
                    int mi = NPI - 1 - (int)(sh.p2.key[i] & 0xFFFFFFFFu);
                    float bx1 = sh.p2.box[mi][0], by1 = sh.p2.box[mi][1];
                    float bx2 = sh.p2.box[mi][2], by2 = sh.p2.box[mi][3];
                    sh.p2.sbox[i][0] = bx1; sh.p2.sbox[i][1] = by1;
                    sh.p2.sbox[i][2] = bx2; sh.p2.sbox[i][3] = by2;
                    sh.p2.sarea[i] = (bx2 - bx1 + 1.f) * (by2 - by1 + 1.f);
                }
                __syncthreads();
                int nwords = ((n + 63) >> 6);
                for (int w = t; w < n * (FASTN/64); w += 256) {
                    int i = w >> 2, wb = w & 3;
                    if (wb >= nwords || ((wb + 1) << 6) - 1 <= i) { sh.p2.mask[i][wb] = 0ULL; continue; }
                    float ax1 = sh.p2.sbox[i][0], ay1 = sh.p2.sbox[i][1];
                    float ax2 = sh.p2.sbox[i][2], ay2 = sh.p2.sbox[i][3];
                    float aarea = sh.p2.sarea[i];
                    unsigned long long bits = 0ULL;
                    int jbase = wb << 6;
                    #pragma unroll 4
                    for (int b = 0; b < 64; ++b) {
                        int j = jbase + b;
                        if (j < n && j > i) {
                            float bx1 = sh.p2.sbox[j][0], by1 = sh.p2.sbox[j][1];
                            float bx2 = sh.p2.sbox[j][2], by2 = sh.p2.sbox[j][3];
                            float xx1 = fmaxf(ax1, bx1), yy1 = fmaxf(ay1, by1);
                            float xx2 = fminf(ax2, bx2), yy2 = fminf(ay2, by2);
                            float iw = fmaxf(xx2 - xx1 + 1.f, 0.f);
                            float ih = fmaxf(yy2 - yy1 + 1.f, 0.f);
                            float inter = iw * ih;
                            float iou = inter / (aarea + sh.p2.sarea[j] - inter);
                            if (iou > NMS_T) bits |= (1ULL << b);
                        }
                    }
                    sh.p2.mask[i][wb] = bits;
                }
                __syncthreads();
                if (t < 64) {
                    int lane = t;
                    unsigned long long kb = 0ULL;
                    if (lane < 4) {
                        int rem = n - (lane << 6);
                        if (rem >= 64) kb = ~0ULL;
                        else if (rem > 0) kb = (1ULL << rem) - 1ULL;
                    }
                    unsigned long long rm = 0ULL;
                    for (int i = 0; i < n; ++i) {
                        unsigned long long rw = __shfl(rm, i >> 6, 64);
                        if (!((rw >> (i & 63)) & 1ULL)) {
                            unsigned long long mrow = (lane < 4) ? sh.p2.mask[i][lane] : 0ULL;
                            rm |= mrow;
                        }
                    }
                    if (lane < 4) sh.p2.keepw[lane] = kb & ~rm;
                }
                __syncthreads();
                for (int i = t; i < n; i += 256)
                    sh.p2.keep[i] = (int)((sh.p2.keepw[i >> 6] >> (i & 63)) & 1ULL);
                __syncthreads();
            } else {
                for (int i = t; i < n; i += 256) sh.p2.keep[i] = 1;
                __syncthreads();
                for (int i = 0; i < n; ++i) {
                    if (sh.p2.keep[i]) {
                        unsigned long long ki = sh.p2.key[i];
                        int mi = NPI - 1 - (int)(ki & 0xFFFFFFFFu);
                        float ax1 = sh.p2.box[mi][0], ay1 = sh.p2.box[mi][1];
                        float ax2 = sh.p2.box[mi][2], ay2 = sh.p2.box[mi][3];
                        float aarea = (ax2 - ax1 + 1.f) * (ay2 - ay1 + 1.f);
                        for (int jj = i + 1 + t; jj < n; jj += 256) {
                            if (sh.p2.keep[jj]) {
                                int mj = NPI - 1 - (int)(sh.p2.key[jj] & 0xFFFFFFFFu);
                                float bx1 = sh.p2.box[mj][0], by1 = sh.p2.box[mj][1];
                                float bx2 = sh.p2.box[mj][2], by2 = sh.p2.box[mj][3];
                                float xx1 = fmaxf(ax1, bx1), yy1 = fmaxf(ay1, by1);
                                float xx2 = fminf(ax2, bx2), yy2 = fminf(ay2, by2);
                                float iw = fmaxf(xx2 - xx1 + 1.f, 0.f);
                                float ih = fmaxf(yy2 - yy1 + 1.f, 0.f);
                                float inter = iw * ih;
                                float barea = (bx2 - bx1 + 1.f) * (by2 - by1 + 1.f);
                                float iou = inter / (aarea + barea - inter);
                                if (iou > NMS_T) sh.p2.keep[jj] = 0;
                            }
                        }
                    }
                    __syncthreads();
                }
            }

            // parallel compaction
            {
                int lane = t & 63, w = t >> 6;
                int k0 = sh.p2.keep[4 * t], k1 = sh.p2.keep[4 * t + 1];
                int k2 = sh.p2.keep[4 * t + 2], k3 = sh.p2.keep[4 * t + 3];
                unsigned s = (unsigned)(k0 + k1 + k2 + k3);
                unsigned v = s;
                #pragma unroll
                for (int off = 1; off < 64; off <<= 1) {
                    unsigned u = __shfl_up(v, off, 64);
                    v += (lane >= off) ? u : 0u;
                }
                if (lane == 63) sh.p2.wpre[w] = v;
                __syncthreads();
                unsigned woff = 0;
                for (int w2 = 0; w2 < w; ++w2) woff += sh.p2.wpre[w2];
                unsigned r = v + woff - s;
                #pragma unroll
                for (int j = 0; j < 4; ++j) {
                    int i = 4 * t + j;
                    int kv = (j == 0) ? k0 : (j == 1) ? k1 : (j == 2) ? k2 : k3;
                    if (kv && r < DETS) {
                        unsigned long long ki = sh.p2.key[i];
                        int mi = NPI - 1 - (int)(ki & 0xFFFFFFFFu);
                        int slot = pid * DETS + (int)r;
                        escore[slot] = __uint_as_float((unsigned)(ki >> 32));
                        ekey[slot] = (unsigned)(c * NPI + i);
                        ebox[slot * 4 + 0] = sh.p2.box[mi][0];
                        ebox[slot * 4 + 1] = sh.p2.box[mi][1];
                        ebox[slot * 4 + 2] = sh.p2.box[mi][2];
                        ebox[slot * 4 + 3] = sh.p2.box[mi][3];
                    }
                    r += (unsigned)kv;
                }
                __syncthreads();
                if (t == 0) {
                    unsigned tot = sh.p2.wpre[0] + sh.p2.wpre[1] + sh.p2.wpre[2] + sh.p2.wpre[3];
                    gcnt[pid] = (int)(tot < DETS ? tot : DETS);
                }
            }
        }
        __syncthreads();   // protect cnt/key reset of next iteration
    }
    grid.sync();

    // ============ Phase 3: per-image top-100 merge (blocks 0..7) ============
    if (bid < NIMG) {
        int img = bid;
        if (t < NFG) sh.p3.cnts[t] = gcnt[img * NFG + t];
        if (t == 0) { sh.p3.B1 = 0; sh.p3.B2 = 0; sh.p3.Nc = 0; sh.p3.Ab1 = 0; sh.p3.Ab2 = 0; }
        for (int i = t; i < 4096; i += 256) sh.p3.hist[i] = 0;
        __syncthreads();

        for (int p = t; p < NCAND; p += 256) {
            if ((p % DETS) < sh.p3.cnts[p / DETS]) {
                unsigned fb = __float_as_uint(escore[img * NCAND + p]);
                atomicAdd(&sh.p3.hist[fb >> 19], 1u);
            }
        }
        __syncthreads();
        suffix_select256(sh.p3.hist, sh.p3.wtot, DETS, &sh.p3.B1, &sh.p3.Ab1);
        int B1 = sh.p3.B1; unsigned ab1 = sh.p3.Ab1;

        for (int i = t; i < 4096; i += 256) sh.p3.hist[i] = 0;
        __syncthreads();
        for (int p = t; p < NCAND; p += 256) {
            if ((p % DETS) < sh.p3.cnts[p / DETS]) {
                unsigned fb = __float_as_uint(escore[img * NCAND + p]);
                if ((int)(fb >> 19) == B1) atomicAdd(&sh.p3.hist[(fb >> 7) & 0xFFFu], 1u);
            }
        }
        __syncthreads();
        suffix_select256(sh.p3.hist, sh.p3.wtot, DETS - (int)ab1, &sh.p3.B2, &sh.p3.Ab2);
        int B2 = sh.p3.B2;

        for (int p = t; p < NCAND; p += 256) {
            if ((p % DETS) < sh.p3.cnts[p / DETS]) {
                unsigned fb = __float_as_uint(escore[img * NCAND + p]);
                int d1 = (int)(fb >> 19);
                bool ok = d1 > B1 || (d1 == B1 && (int)((fb >> 7) & 0xFFFu) >= B2);
                if (ok) {
                    int pos = atomicAdd(&sh.p3.Nc, 1);
                    if (pos < CAND_CAP) {
                        unsigned fk = ekey[img * NCAND + p];
                        sh.p3.cand[pos] = ((unsigned long long)fb << 32)
                                        | (((0x1FFFFu - fk) << 13) | (unsigned)p);
                    }
                }
            }
        }
        __syncthreads();
        int nc = sh.p3.Nc < CAND_CAP ? sh.p3.Nc : CAND_CAP;
        int P = 128;
        while (P < nc) P <<= 1;
        for (int i = t; i < P; i += 256)
            if (i >= nc) sh.p3.cand[i] = 0ULL;
        __syncthreads();

        for (int k = 2; k <= P; k <<= 1) {
            for (int j = k >> 1; j > 0; j >>= 1) {
                for (int i = t; i < P; i += 256) {
                    int ixj = i ^ j;
                    if (ixj > i) {
                        unsigned long long a = sh.p3.cand[i], b = sh.p3.cand[ixj];
                        bool up = (i & k) == 0;
                        if (up ? (a < b) : (a > b)) { sh.p3.cand[i] = b; sh.p3.cand[ixj] = a; }
                    }
                }
                __syncthreads();
            }
        }

        float* oScore = out;
        float* oBox   = out + NIMG * DETS;
        float* oLab   = out + NIMG * DETS * 5;

        if (t < DETS) {
            unsigned long long b = sh.p3.cand[t];
            int o = img * DETS + t;
            if (b != 0ULL) {
                float scv = __uint_as_float((unsigned)(b >> 32));
                unsigned low = (unsigned)(b & 0xFFFFFFFFu);
                unsigned flatkey = 0x1FFFFu - ((low >> 13) & 0x1FFFFu);
                int p = (int)(low & 0x1FFFu);
                int gp = img * NCAND + p;
                oScore[o] = scv;
                oBox[o * 4 + 0] = ebox[gp * 4 + 0];
                oBox[o * 4 + 1] = ebox[gp * 4 + 1];
                oBox[o * 4 + 2] = ebox[gp * 4 + 2];
                oBox[o * 4 + 3] = ebox[gp * 4 + 3];
                oLab[o] = (float)((flatkey >> 10) + 1);
            } else {
                oScore[o] = 0.f;
                oBox[o * 4 + 0] = 0.f; oBox[o * 4 + 1] = 0.f;
                oBox[o * 4 + 2] = 0.f; oBox[o * 4 + 3] = 0.f;
                oLab[o] = 0.f;
            }
        }
    }
}

// ======================= R5 fallback kernels (proven) =======================
__global__ __launch_bounds__(256) void softmax_probT(
    const float* __restrict__ logits, float* __restrict__ probT, int M)
{
    __shared__ float tile[ROWS * NCLS];
    __shared__ float mx[ROWS], dn[ROWS];
    int t = threadIdx.x;
    int rbase = blockIdx.x * ROWS;
    for (int idx = t; idx < ROWS * NCLS; idx += 256)
        tile[idx] = logits[(size_t)rbase * NCLS + idx];
    __syncthreads();
    if (t < ROWS) {
        const float* r = tile + t * NCLS;
        float m = r[0];
        #pragma unroll
        for (int j = 1; j < NCLS; ++j) m = fmaxf(m, r[j]);
        float s = 0.f;
        #pragma unroll
        for (int j = 0; j < NCLS; ++j) s += expf(r[j] - m);
        mx[t] = m; dn[t] = s;
    }
    __syncthreads();
    for (int o = t; o < ROWS * NFG; o += 256) {
        int r = o & 63;
        int c = o >> 6;
        probT[(size_t)c * M + rbase + r] = expf(tile[r * NCLS + (c + 1)] - mx[r]) / dn[r];
    }
}

__global__ __launch_bounds__(256) void per_class_nms(
    const float* __restrict__ probT, const float* __restrict__ boxreg,
    const float* __restrict__ props, const int* __restrict__ hptr,
    const int* __restrict__ wptr, int* __restrict__ out_cnt,
    float* __restrict__ out_score, unsigned* __restrict__ out_key,
    float* __restrict__ out_box, int M)
{
    int pid = blockIdx.x;
    int img = pid / NFG;
    int c   = pid % NFG;
    int cls = c + 1;
    __shared__ ShP2 sp;
    __shared__ int cnt;
    int t = threadIdx.x;
    float W1 = (float)(*wptr - 1);
    float H1 = (float)(*hptr - 1);

    if (t == 0) cnt = 0;
    for (int i = t; i < NPI; i += 256) sp.key[i] = 0ULL;
    __syncthreads();
    {
        const float4 pv = *(const float4*)(probT + (size_t)c * M + img * NPI + 4 * t);
        float pr[4] = {pv.x, pv.y, pv.z, pv.w};
        #pragma unroll
        for (int j = 0; j < 4; ++j) {
            if (pr[j] > SCORE_T) {
                int m = 4 * t + j;
                int g = img * NPI + m;
                const float4 pb = *(const float4*)(props + (size_t)g * 4);
                float x1 = pb.x, y1 = pb.y, x2 = pb.z, y2 = pb.w;
                float w  = x2 - x1 + 1.0f, h = y2 - y1 + 1.0f;
                float cx = x1 + 0.5f * w,  cy = y1 + 0.5f * h;
                const float4 rc = *(const float4*)(boxreg + (size_t)g * (4 * NCLS) + 4 * cls);
                float dx = rc.x / 10.0f, dy = rc.y / 10.0f;
                float dw = fminf(rc.z / 5.0f, BBOX_CLIP);
                float dh = fminf(rc.w / 5.0f, BBOX_CLIP);
                float pcx = dx * w + cx, pcy = dy * h + cy;
                float pw = expf(dw) * w, ph = expf(dh) * h;
                float bx1 = fminf(fmaxf(pcx - 0.5f * pw, 0.f), W1);
                float by1 = fminf(fmaxf(pcy - 0.5f * ph, 0.f), H1);
                float bx2 = fminf(fmaxf(pcx + 0.5f * pw - 1.0f, 0.f), W1);
                float by2 = fminf(fmaxf(pcy + 0.5f * ph - 1.0f, 0.f), H1);
                sp.box[m][0] = bx1; sp.box[m][1] = by1;
                sp.box[m][2] = bx2; sp.box[m][3] = by2;
                int p = atomicAdd(&cnt, 1);
                sp.key[p] = ((unsigned long long)__float_as_uint(pr[j]) << 32)
                          | (unsigned)(NPI - 1 - m);
            }
        }
    }
    __syncthreads();
    int n = cnt;

    if (n <= 64) {
        if (t < 64) {
            int lane = t;
            unsigned long long k = (lane < n) ? sp.key[lane] : 0ULL;
            #pragma unroll
            for (int kk = 2; kk <= 64; kk <<= 1) {
                #pragma unroll
                for (int j = kk >> 1; j > 0; j >>= 1) {
                    unsigned long long o = __shfl_xor(k, j, 64);
                    bool take_max = (((lane & kk) == 0) == ((lane & j) == 0));
                    k = take_max ? (k > o ? k : o) : (k < o ? k : o);
                }
            }
            bool valid = (lane < n);
            float bx1 = 0.f, by1 = 0.f, bx2 = 0.f, by2 = 0.f, area = 0.f;
            if (valid) {
                int mi = NPI - 1 - (int)(k & 0xFFFFFFFFu);
                bx1 = sp.box[mi][0]; by1 = sp.box[mi][1];
                bx2 = sp.box[mi][2]; by2 = sp.box[mi][3];
                area = (bx2 - bx1 + 1.f) * (by2 - by1 + 1.f);
            }
            unsigned long long sup = 0ULL;
            for (int i = 0; i < n; ++i) {
                bool alive = !((sup >> i) & 1ULL);
                float ax1 = __shfl(bx1, i, 64), ay1 = __shfl(by1, i, 64);
                float ax2 = __shfl(bx2, i, 64), ay2 = __shfl(by2, i, 64);
                float aarea = __shfl(area, i, 64);
                bool s = false;
                if (alive && valid && lane > i) {
                    float xx1 = fmaxf(ax1, bx1), yy1 = fmaxf(ay1, by1);
                    float xx2 = fminf(ax2, bx2), yy2 = fminf(ay2, by2);
                    float iw = fmaxf(xx2 - xx1 + 1.f, 0.f);
                    float ih = fmaxf(yy2 - yy1 + 1.f, 0.f);
                    float inter = iw * ih;
                    s = inter / (aarea + area - inter) > NMS_T;
                }
                sup |= __ballot(s);
            }
            bool kept = valid && !((sup >> lane) & 1ULL);
            unsigned long long keptm = __ballot(kept);
            int rank = __popcll(keptm & ((1ULL << lane) - 1ULL));
            if (kept && rank < DETS) {
                int slot = pid * DETS + rank;
                out_score[slot] = __uint_as_float((unsigned)(k >> 32));
                out_key[slot] = (unsigned)(c * NPI + lane);
                out_box[slot * 4 + 0] = bx1; out_box[slot * 4 + 1] = by1;
                out_box[slot * 4 + 2] = bx2; out_box[slot * 4 + 3] = by2;
            }
            if (lane == 0) {
                int tot = __popcll(keptm);
                out_cnt[pid] = tot < DETS ? tot : DETS;
            }
        }
        return;
    }

    int P = 2;
    while (P < n) P <<= 1;
    for (int k = 2; k <= P; k <<= 1) {
        for (int j = k >> 1; j > 0; j >>= 1) {
            for (int i = t; i < P; i += 256) {
                int ixj = i ^ j;
                if (ixj > i) {
                    unsigned long long a = sp.key[i], b = sp.key[ixj];
                    bool up = (i & k) == 0;
                    if (up ? (a < b) : (a > b)) { sp.key[i] = b; sp.key[ixj] = a; }
                }
            }
            __syncthreads();
        }
    }
    for (int i = t; i < NPI; i += 256) sp.keep[i] = 0;
    __syncthreads();

    if (n <= FASTN) {
        for (int i = t; i < n; i += 256) {
            int mi = NPI - 1 - (int)(sp.key[i] & 0xFFFFFFFFu);
            float bx1 = sp.box[mi][0], by1 = sp.box[mi][1];
            float bx2 = sp.box[mi][2], by2 = sp.box[mi][3];
            sp.sbox[i][0] = bx1; sp.sbox[i][1] = by1;
            sp.sbox[i][2] = bx2; sp.sbox[i][3] = by2;
            sp.sarea[i] = (bx2 - bx1 + 1.f) * (by2 - by1 + 1.f);
        }
        __syncthreads();
        int nwords = ((n + 63) >> 6);
        for (int w = t; w < n * (FASTN/64); w += 256) {
            int i = w >> 2, wb = w & 3;
            if (wb >= nwords || ((wb + 1) << 6) - 1 <= i) { sp.mask[i][wb] = 0ULL; continue; }
            float ax1 = sp.sbox[i][0], ay1 = sp.sbox[i][1];
            float ax2 = sp.sbox[i][2], ay2 = sp.sbox[i][3];
            float aarea = sp.sarea[i];
            unsigned long long bits = 0ULL;
            int jbase = wb << 6;
            #pragma unroll 4
            for (int b = 0; b < 64; ++b) {
                int j = jbase + b;
                if (j < n && j > i) {
                    float bx1 = sp.sbox[j][0], by1 = sp.sbox[j][1];
                    float bx2 = sp.sbox[j][2], by2 = sp.sbox[j][3];
                    float xx1 = fmaxf(ax1, bx1), yy1 = fmaxf(ay1, by1);
                    float xx2 = fminf(ax2, bx2), yy2 = fminf(ay2, by2);
                    float iw = fmaxf(xx2 - xx1 + 1.f, 0.f);
                    float ih = fmaxf(yy2 - yy1 + 1.f, 0.f);
                    float inter = iw * ih;
                    if (inter / (aarea + sp.sarea[j] - inter) > NMS_T) bits |= (1ULL << b);
                }
            }
            sp.mask[i][wb] = bits;
        }
        __syncthreads();
        if (t < 64) {
            int lane = t;
            unsigned long long kb = 0ULL;
            if (lane < 4) {
                int rem = n - (lane << 6);
                if (rem >= 64) kb = ~0ULL;
                else if (rem > 0) kb = (1ULL << rem) - 1ULL;
            }
            unsigned long long rm = 0ULL;
            for (int i = 0; i < n; ++i) {
                unsigned long long rw = __shfl(rm, i >> 6, 64);
                if (!((rw >> (i & 63)) & 1ULL)) {
                    unsigned long long mrow = (lane < 4) ? sp.mask[i][lane] : 0ULL;
                    rm |= mrow;
                }
            }
            if (lane < 4) sp.keepw[lane] = kb & ~rm;
        }
        __syncthreads();
        for (int i = t; i < n; i += 256)
            sp.keep[i] = (int)((sp.keepw[i >> 6] >> (i & 63)) & 1ULL);
        __syncthreads();
    } else {
        for (int i = t; i < n; i += 256) sp.keep[i] = 1;
        __syncthreads();
        for (int i = 0; i < n; ++i) {
            if (sp.keep[i]) {
                unsigned long long ki = sp.key[i];
                int mi = NPI - 1 - (int)(ki & 0xFFFFFFFFu);
                float ax1 = sp.box[mi][0], ay1 = sp.box[mi][1];
                float ax2 = sp.box[mi][2], ay2 = sp.box[mi][3];
                float aarea = (ax2 - ax1 + 1.f) * (ay2 - ay1 + 1.f);
                for (int jj = i + 1 + t; jj < n; jj += 256) {
                    if (sp.keep[jj]) {
                        int mj = NPI - 1 - (int)(sp.key[jj] & 0xFFFFFFFFu);
                        float bx1 = sp.box[mj][0], by1 = sp.box[mj][1];
                        float bx2 = sp.box[mj][2], by2 = sp.box[mj][3];
                        float xx1 = fmaxf(ax1, bx1), yy1 = fmaxf(ay1, by1);
                        float xx2 = fminf(ax2, bx2), yy2 = fminf(ay2, by2);
                        float iw = fmaxf(xx2 - xx1 + 1.f, 0.f);
                        float ih = fmaxf(yy2 - yy1 + 1.f, 0.f);
                        float inter = iw * ih;
                        float barea = (bx2 - bx1 + 1.f) * (by2 - by1 + 1.f);
                        if (inter / (aarea + barea - inter) > NMS_T) sp.keep[jj] = 0;
                    }
                }
            }
            __syncthreads();
        }
    }
    {
        int lane = t & 63, w = t >> 6;
        int k0 = sp.keep[4 * t], k1 = sp.keep[4 * t + 1];
        int k2 = sp.keep[4 * t + 2], k3 = sp.keep[4 * t + 3];
        unsigned s = (unsigned)(k0 + k1 + k2 + k3);
        unsigned v = s;
        #pragma unroll
        for (int off = 1; off < 64; off <<= 1) {
            unsigned u = __shfl_up(v, off, 64);
            v += (lane >= off) ? u : 0u;
        }
        if (lane == 63) sp.wpre[w] = v;
        __syncthreads();
        unsigned woff = 0;
        for (int w2 = 0; w2 < w; ++w2) woff += sp.wpre[w2];
        unsigned r = v + woff - s;
        #pragma unroll
        for (int j = 0; j < 4; ++j) {
            int i = 4 * t + j;
            int kv = (j == 0) ? k0 : (j == 1) ? k1 : (j == 2) ? k2 : k3;
            if (kv && r < DETS) {
                unsigned long long ki = sp.key[i];
                int mi = NPI - 1 - (int)(ki & 0xFFFFFFFFu);
                int slot = pid * DETS + (int)r;
                out_score[slot] = __uint_as_float((unsigned)(ki >> 32));
                out_key[slot] = (unsigned)(c * NPI + i);
                out_box[slot * 4 + 0] = sp.box[mi][0];
                out_box[slot * 4 + 1] = sp.box[mi][1];
                out_box[slot * 4 + 2] = sp.box[mi][2];
                out_box[slot * 4 + 3] = sp.box[mi][3];
            }
            r += (unsigned)kv;
        }
        __syncthreads();
        if (t == 0) {
            unsigned tot = sp.wpre[0] + sp.wpre[1] + sp.wpre[2] + sp.wpre[3];
            out_cnt[pid] = (int)(tot < DETS ? tot : DETS);
        }
    }
}

__global__ __launch_bounds__(256) void topk_merge(
    const int* __restrict__ cnts, const float* __restrict__ escore,
    const unsigned* __restrict__ ekey, const float* __restrict__ ebox,
    float* __restrict__ out)
{
    int img = blockIdx.x;
    __shared__ ShP3 s3;
    int t = threadIdx.x;
    if (t < NFG) s3.cnts[t] = cnts[img * NFG + t];
    if (t == 0) { s3.B1 = 0; s3.B2 = 0; s3.Nc = 0; s3.Ab1 = 0; s3.Ab2 = 0; }
    for (int i = t; i < 4096; i += 256) s3.hist[i] = 0;
    __syncthreads();
    for (int p = t; p < NCAND; p += 256) {
        if ((p % DETS) < s3.cnts[p / DETS]) {
            unsigned fb = __float_as_uint(escore[img * NCAND + p]);
            atomicAdd(&s3.hist[fb >> 19], 1u);
        }
    }
    __syncthreads();
    suffix_select256(s3.hist, s3.wtot, DETS, &s3.B1, &s3.Ab1);
    int B1 = s3.B1; unsigned ab1 = s3.Ab1;
    for (int i = t; i < 4096; i += 256) s3.hist[i] = 0;
    __syncthreads();
    for (int p = t; p < NCAND; p += 256) {
        if ((p % DETS) < s3.cnts[p / DETS]) {
            unsigned fb = __float_as_uint(escore[img * NCAND + p]);
            if ((int)(fb >> 19) == B1) atomicAdd(&s3.hist[(fb >> 7) & 0xFFFu], 1u);
        }
    }
    __syncthreads();
    suffix_select256(s3.hist, s3.wtot, DETS - (int)ab1, &s3.B2, &s3.Ab2);
    int B2 = s3.B2;
    for (int p = t; p < NCAND; p += 256) {
        if ((p % DETS) < s3.cnts[p / DETS]) {
            unsigned fb = __float_as_uint(escore[img * NCAND + p]);
            int d1 = (int)(fb >> 19);
            bool ok = d1 > B1 || (d1 == B1 && (int)((fb >> 7) & 0xFFFu) >= B2);
            if (ok) {
                int pos = atomicAdd(&s3.Nc, 1);
                if (pos < CAND_CAP) {
                    unsigned fk = ekey[img * NCAND + p];
                    s3.cand[pos] = ((unsigned long long)fb << 32)
                                 | (((0x1FFFFu - fk) << 13) | (unsigned)p);
                }
            }
        }
    }
    __syncthreads();
    int nc = s3.Nc < CAND_CAP ? s3.Nc : CAND_CAP;
    int P = 128;
    while (P < nc) P <<= 1;
    for (int i = t; i < P; i += 256)
        if (i >= nc) s3.cand[i] = 0ULL;
    __syncthreads();
    for (int k = 2; k <= P; k <<= 1) {
        for (int j = k >> 1; j > 0; j >>= 1) {
            for (int i = t; i < P; i += 256) {
                int ixj = i ^ j;
                if (ixj > i) {
                    unsigned long long a = s3.cand[i], b = s3.cand[ixj];
                    bool up = (i & k) == 0;
                    if (up ? (a < b) : (a > b)) { s3.cand[i] = b; s3.cand[ixj] = a; }
                }
            }
            __syncthreads();
        }
    }
    float* oScore = out;
    float* oBox   = out + NIMG * DETS;
    float* oLab   = out + NIMG * DETS * 5;
    if (t < DETS) {
        unsigned long long b = s3.cand[t];
        int o = img * DETS + t;
        if (b != 0ULL) {
            float scv = __uint_as_float((unsigned)(b >> 32));
            unsigned low = (unsigned)(b & 0xFFFFFFFFu);
            unsigned flatkey = 0x1FFFFu - ((low >> 13) & 0x1FFFFu);
            int p = (int)(low & 0x1FFFu);
            int gp = img * NCAND + p;
            oScore[o] = scv;
            oBox[o * 4 + 0] = ebox[gp * 4 + 0];
            oBox[o * 4 + 1] = ebox[gp * 4 + 1];
            oBox[o * 4 + 2] = ebox[gp * 4 + 2];
            oBox[o * 4 + 3] = ebox[gp * 4 + 3];
            oLab[o] = (float)((flatkey >> 10) + 1);
        } else {
            oScore[o] = 0.f;
            oBox[o * 4 + 0] = 0.f; oBox[o * 4 + 1] = 0.f;
            oBox[o * 4 + 2] = 0.f; oBox[o * 4 + 3] = 0.f;
            oLab[o] = 0.f;
        }
    }
}

extern "C" void kernel_launch(void* const* d_in, const int* in_sizes, int n_in,
                              void* d_out, int out_size, void* d_ws, size_t ws_size,
                              hipStream_t stream) {
    const float* logits = (const float*)d_in[0];
    const float* boxreg = (const float*)d_in[1];
    const float* props  = (const float*)d_in[2];
    const int*   hptr   = (const int*)d_in[3];
    const int*   wptr   = (const int*)d_in[4];
    float* out = (float*)d_out;
    int M = in_sizes[0] / NCLS; // 8192

    char* ws = (char*)d_ws;
    float*    probT  = (float*)ws;    ws += (size_t)NFG * M * sizeof(float);
    int*      gcnt   = (int*)ws;      ws += (size_t)NIMG * NFG * sizeof(int);
    float*    escore = (float*)ws;    ws += (size_t)NIMG * NCAND * sizeof(float);
    unsigned* ekey   = (unsigned*)ws; ws += (size_t)NIMG * NCAND * sizeof(unsigned);
    float*    ebox   = (float*)ws;    ws += (size_t)NIMG * NCAND * 4 * sizeof(float);

    void* args[] = {
        (void*)&logits, (void*)&boxreg, (void*)&props, (void*)&hptr, (void*)&wptr,
        (void*)&probT, (void*)&gcnt, (void*)&escore, (void*)&ekey, (void*)&ebox,
        (void*)&out, (void*)&M
    };
    hipError_t err = hipLaunchCooperativeKernel(
        reinterpret_cast<void*>(fpn_fused), dim3(GRID_BLOCKS), dim3(256),
        args, 0, stream);
    if (err != hipSuccess) {
        (void)hipGetLastError();  // clear error state; use proven 3-kernel path
        softmax_probT<<<M / ROWS, 256, 0, stream>>>(logits, probT, M);
        per_class_nms<<<NIMG * NFG, 256, 0, stream>>>(
            probT, boxreg, props, hptr, wptr, gcnt, escore, ekey, ebox, M);
        topk_merge<<<NIMG, 256, 0, stream>>>(gcnt, escore, ekey, ebox, out);
    }
}

// Round 8
// 105.805 us; speedup vs baseline: 1.7270x; 1.7270x over previous
//
#include <hip/hip_runtime.h>
#include <stdint.h>
#include <math.h>

#define NCLS 81
#define NFG  80
#define NPI  1024
#define NIMG 8
#define DETS 100
#define SCORE_T 0.05f
#define NMS_T   0.5f
#define NCAND   (NFG * DETS)   // 8000
#define CAND_CAP 2048
#define FASTN 256              // block bitmask-NMS path limit
#define ROWS 64                // rows per stats block

static constexpr float BBOX_CLIP = 4.1351665567423557f; // log(1000/16)

struct ShP2 {
    float box[NPI][4];                         // 16KB (by proposal id)
    unsigned long long key[NPI];               // 8KB
    int keep[NPI];                             // 4KB
    float sbox[FASTN][4];                      // 4KB
    float sarea[FASTN];                        // 1KB
    unsigned long long mask[FASTN][FASTN/64];  // 8KB
    unsigned long long keepw[FASTN/64];
    unsigned wpre[4];
};
struct ShP3 {
    unsigned hist[4096];                       // 16KB
    unsigned long long cand[CAND_CAP];         // 16KB
    int cnts[NFG];
    unsigned wtot[4];
    int B1, B2, Nc;
    unsigned Ab1, Ab2;
};
union ShU { ShP2 p2; ShP3 p3; };

// ---- 256-thread suffix radix-select: bucket B with above(B) < K <= above(B)+cnt(B)
__device__ __forceinline__ void suffix_select256(
    unsigned* hist, unsigned* wtot, int K, int* outB, unsigned* outAbove)
{
    int t = threadIdx.x, lane = t & 63, w = t >> 6;
    unsigned loc[16]; unsigned ps = 0;
    #pragma unroll
    for (int j = 0; j < 16; ++j) { loc[j] = hist[t * 16 + j]; ps += loc[j]; }
    unsigned v = ps;
    #pragma unroll
    for (int off = 1; off < 64; off <<= 1) {
        unsigned u = __shfl_down(v, off, 64);
        v += (lane + off < 64) ? u : 0u;
    }
    if (lane == 0) wtot[w] = v;
    __syncthreads();
    unsigned woff = 0;
    for (int w2 = w + 1; w2 < 4; ++w2) woff += wtot[w2];
    unsigned base = v + woff - ps;
    unsigned suf = 0;
    #pragma unroll
    for (int j = 15; j >= 0; --j) {
        unsigned A = base + suf;
        if ((int)A < K && (int)(A + loc[j]) >= K) { *outB = t * 16 + j; *outAbove = A; }
        suf += loc[j];
    }
    __syncthreads();
}

// ---- per-image top-100 merge (proven R5 logic), run by the last-done block ----
__device__ void merge_image(
    int img, ShP3& s3, const int* gcnt, const float* escore,
    const unsigned* ekey, const float* ebox, float* out)
{
    int t = threadIdx.x;
    if (t < NFG) s3.cnts[t] = gcnt[img * NFG + t];
    if (t == 0) { s3.B1 = 0; s3.B2 = 0; s3.Nc = 0; s3.Ab1 = 0; s3.Ab2 = 0; }
    for (int i = t; i < 4096; i += 256) s3.hist[i] = 0;
    __syncthreads();
    for (int p = t; p < NCAND; p += 256) {
        if ((p % DETS) < s3.cnts[p / DETS]) {
            unsigned fb = __float_as_uint(escore[img * NCAND + p]);
            atomicAdd(&s3.hist[fb >> 19], 1u);
        }
    }
    __syncthreads();
    suffix_select256(s3.hist, s3.wtot, DETS, &s3.B1, &s3.Ab1);
    int B1 = s3.B1; unsigned ab1 = s3.Ab1;
    for (int i = t; i < 4096; i += 256) s3.hist[i] = 0;
    __syncthreads();
    for (int p = t; p < NCAND; p += 256) {
        if ((p % DETS) < s3.cnts[p / DETS]) {
            unsigned fb = __float_as_uint(escore[img * NCAND + p]);
            if ((int)(fb >> 19) == B1) atomicAdd(&s3.hist[(fb >> 7) & 0xFFFu], 1u);
        }
    }
    __syncthreads();
    suffix_select256(s3.hist, s3.wtot, DETS - (int)ab1, &s3.B2, &s3.Ab2);
    int B2 = s3.B2;
    for (int p = t; p < NCAND; p += 256) {
        if ((p % DETS) < s3.cnts[p / DETS]) {
            unsigned fb = __float_as_uint(escore[img * NCAND + p]);
            int d1 = (int)(fb >> 19);
            bool ok = d1 > B1 || (d1 == B1 && (int)((fb >> 7) & 0xFFFu) >= B2);
            if (ok) {
                int pos = atomicAdd(&s3.Nc, 1);
                if (pos < CAND_CAP) {
                    unsigned fk = ekey[img * NCAND + p];
                    s3.cand[pos] = ((unsigned long long)fb << 32)
                                 | (((0x1FFFFu - fk) << 13) | (unsigned)p);
                }
            }
        }
    }
    __syncthreads();
    int nc = s3.Nc < CAND_CAP ? s3.Nc : CAND_CAP;
    int P = 128;
    while (P < nc) P <<= 1;
    for (int i = t; i < P; i += 256)
        if (i >= nc) s3.cand[i] = 0ULL;
    __syncthreads();
    for (int k = 2; k <= P; k <<= 1) {
        for (int j = k >> 1; j > 0; j >>= 1) {
            for (int i = t; i < P; i += 256) {
                int ixj = i ^ j;
                if (ixj > i) {
                    unsigned long long a = s3.cand[i], b = s3.cand[ixj];
                    bool up = (i & k) == 0;
                    if (up ? (a < b) : (a > b)) { s3.cand[i] = b; s3.cand[ixj] = a; }
                }
            }
            __syncthreads();
        }
    }
    float* oScore = out;
    float* oBox   = out + NIMG * DETS;
    float* oLab   = out + NIMG * DETS * 5;
    if (t < DETS) {
        unsigned long long b = s3.cand[t];
        int o = img * DETS + t;
        if (b != 0ULL) {
            float scv = __uint_as_float((unsigned)(b >> 32));
            unsigned low = (unsigned)(b & 0xFFFFFFFFu);
            unsigned flatkey = 0x1FFFFu - ((low >> 13) & 0x1FFFFu);
            int p = (int)(low & 0x1FFFu);
            int gp = img * NCAND + p;
            oScore[o] = scv;
            oBox[o * 4 + 0] = ebox[gp * 4 + 0];
            oBox[o * 4 + 1] = ebox[gp * 4 + 1];
            oBox[o * 4 + 2] = ebox[gp * 4 + 2];
            oBox[o * 4 + 3] = ebox[gp * 4 + 3];
            oLab[o] = (float)((flatkey >> 10) + 1);
        } else {
            oScore[o] = 0.f;
            oBox[o * 4 + 0] = 0.f; oBox[o * 4 + 1] = 0.f;
            oBox[o * 4 + 2] = 0.f; oBox[o * 4 + 3] = 0.f;
            oLab[o] = 0.f;
        }
    }
}

// ---------------- Kernel 1: per-row softmax stats (+ zero done[]) ----------------
__global__ __launch_bounds__(256) void row_stats(
    const float* __restrict__ logits, float* __restrict__ mxout,
    float* __restrict__ dnout, int* __restrict__ done, int M)
{
    __shared__ float tile[ROWS * NCLS];
    int t = threadIdx.x;
    int rbase = blockIdx.x * ROWS;
    if (blockIdx.x == 0 && t < NIMG) done[t] = 0;
    for (int idx = t; idx < ROWS * NCLS; idx += 256)
        tile[idx] = logits[(size_t)rbase * NCLS + idx];
    __syncthreads();
    if (t < ROWS) {
        const float* r = tile + t * NCLS;
        float m = r[0];
        #pragma unroll
        for (int j = 1; j < NCLS; ++j) m = fmaxf(m, r[j]);
        float s = 0.f;
        #pragma unroll
        for (int j = 0; j < NCLS; ++j) s += expf(r[j] - m);
        mxout[rbase + t] = m;
        dnout[rbase + t] = s;
    }
}

// ---------------- Kernel 2: per-(image,class) NMS + last-block merge ----------------
__global__ __launch_bounds__(256) void nms_merge(
    const float* __restrict__ logits, const float* __restrict__ boxreg,
    const float* __restrict__ props, const int* __restrict__ hptr,
    const int* __restrict__ wptr, const float* __restrict__ mxin,
    const float* __restrict__ dnin, int* done, int* gcnt,
    float* escore, unsigned* ekey, float* ebox,
    float* __restrict__ out, int M)
{
    int pid = blockIdx.x;           // 0..639
    int img = pid / NFG;
    int c   = pid % NFG;
    int cls = c + 1;

    __shared__ ShU sh;
    __shared__ int cnt;
    __shared__ int lastflag;
    int t = threadIdx.x;
    float W1 = (float)(*wptr - 1);
    float H1 = (float)(*hptr - 1);

    if (t == 0) cnt = 0;
    for (int i = t; i < NPI; i += 256) sh.p2.key[i] = 0ULL;
    __syncthreads();

    // ---- load phase: prob from logits + row stats ----
    {
        const float4 mxv = *(const float4*)(mxin + img * NPI + 4 * t);
        const float4 dnv = *(const float4*)(dnin + img * NPI + 4 * t);
        float mxa[4] = {mxv.x, mxv.y, mxv.z, mxv.w};
        float dna[4] = {dnv.x, dnv.y, dnv.z, dnv.w};
        #pragma unroll
        for (int j = 0; j < 4; ++j) {
            int m = 4 * t + j;
            int g = img * NPI + m;
            float pr = expf(logits[(size_t)g * NCLS + cls] - mxa[j]) / dna[j];
            if (pr > SCORE_T) {
                const float4 pb = *(const float4*)(props + (size_t)g * 4);
                float x1 = pb.x, y1 = pb.y, x2 = pb.z, y2 = pb.w;
                float w  = x2 - x1 + 1.0f, h = y2 - y1 + 1.0f;
                float cx = x1 + 0.5f * w,  cy = y1 + 0.5f * h;
                const float4 rc = *(const float4*)(boxreg + (size_t)g * (4 * NCLS) + 4 * cls);
                float dx = rc.x / 10.0f, dy = rc.y / 10.0f;
                float dw = fminf(rc.z / 5.0f, BBOX_CLIP);
                float dh = fminf(rc.w / 5.0f, BBOX_CLIP);
                float pcx = dx * w + cx, pcy = dy * h + cy;
                float pw = expf(dw) * w, ph = expf(dh) * h;
                float bx1 = fminf(fmaxf(pcx - 0.5f * pw, 0.f), W1);
                float by1 = fminf(fmaxf(pcy - 0.5f * ph, 0.f), H1);
                float bx2 = fminf(fmaxf(pcx + 0.5f * pw - 1.0f, 0.f), W1);
                float by2 = fminf(fmaxf(pcy + 0.5f * ph - 1.0f, 0.f), H1);
                sh.p2.box[m][0] = bx1; sh.p2.box[m][1] = by1;
                sh.p2.box[m][2] = bx2; sh.p2.box[m][3] = by2;
                int p = atomicAdd(&cnt, 1);
                sh.p2.key[p] = ((unsigned long long)__float_as_uint(pr) << 32)
                             | (unsigned)(NPI - 1 - m);
            }
        }
    }
    __syncthreads();
    int n = cnt;

    if (n <= 64) {
        // ---- wave fast path (no barriers) ----
        if (t < 64) {
            int lane = t;
            unsigned long long k = (lane < n) ? sh.p2.key[lane] : 0ULL;
            #pragma unroll
            for (int kk = 2; kk <= 64; kk <<= 1) {
                #pragma unroll
                for (int j = kk >> 1; j > 0; j >>= 1) {
                    unsigned long long o = __shfl_xor(k, j, 64);
                    bool take_max = (((lane & kk) == 0) == ((lane & j) == 0));
                    k = take_max ? (k > o ? k : o) : (k < o ? k : o);
                }
            }
            bool valid = (lane < n);
            float bx1 = 0.f, by1 = 0.f, bx2 = 0.f, by2 = 0.f, area = 0.f;
            if (valid) {
                int mi = NPI - 1 - (int)(k & 0xFFFFFFFFu);
                bx1 = sh.p2.box[mi][0]; by1 = sh.p2.box[mi][1];
                bx2 = sh.p2.box[mi][2]; by2 = sh.p2.box[mi][3];
                area = (bx2 - bx1 + 1.f) * (by2 - by1 + 1.f);
            }
            unsigned long long sup = 0ULL;
            for (int i = 0; i < n; ++i) {
                bool alive = !((sup >> i) & 1ULL);
                float ax1 = __shfl(bx1, i, 64), ay1 = __shfl(by1, i, 64);
                float ax2 = __shfl(bx2, i, 64), ay2 = __shfl(by2, i, 64);
                float aarea = __shfl(area, i, 64);
                bool s = false;
                if (alive && valid && lane > i) {
                    float xx1 = fmaxf(ax1, bx1), yy1 = fmaxf(ay1, by1);
                    float xx2 = fminf(ax2, bx2), yy2 = fminf(ay2, by2);
                    float iw = fmaxf(xx2 - xx1 + 1.f, 0.f);
                    float ih = fmaxf(yy2 - yy1 + 1.f, 0.f);
                    float inter = iw * ih;
                    s = inter / (aarea + area - inter) > NMS_T;
                }
                sup |= __ballot(s);
            }
            bool kept = valid && !((sup >> lane) & 1ULL);
            unsigned long long keptm = __ballot(kept);
            int rank = __popcll(keptm & ((1ULL << lane) - 1ULL));
            if (kept && rank < DETS) {
                int slot = pid * DETS + rank;
                escore[slot] = __uint_as_float((unsigned)(k >> 32));
                ekey[slot] = (unsigned)(c * NPI + lane);
                ebox[slot * 4 + 0] = bx1; ebox[slot * 4 + 1] = by1;
                ebox[slot * 4 + 2] = bx2; ebox[slot * 4 + 3] = by2;
            }
            if (lane == 0) {
                int tot = __popcll(keptm);
                gcnt[pid] = tot < DETS ? tot : DETS;
            }
        }
    } else {
        // ---- block paths ----
        int P = 2;
        while (P < n) P <<= 1;
        for (int k = 2; k <= P; k <<= 1) {
            for (int j = k >> 1; j > 0; j >>= 1) {
                for (int i = t; i < P; i += 256) {
                    int ixj = i ^ j;
                    if (ixj > i) {
                        unsigned long long a = sh.p2.key[i], b = sh.p2.key[ixj];
                        bool up = (i & k) == 0;
                        if (up ? (a < b) : (a > b)) { sh.p2.key[i] = b; sh.p2.key[ixj] = a; }
                    }
                }
                __syncthreads();
            }
        }
        for (int i = t; i < NPI; i += 256) sh.p2.keep[i] = 0;
        __syncthreads();

        if (n <= FASTN) {
            for (int i = t; i < n; i += 256) {
                int mi = NPI - 1 - (int)(sh.p2.key[i] & 0xFFFFFFFFu);
                float bx1 = sh.p2.box[mi][0], by1 = sh.p2.box[mi][1];
                float bx2 = sh.p2.box[mi][2], by2 = sh.p2.box[mi][3];
                sh.p2.sbox[i][0] = bx1; sh.p2.sbox[i][1] = by1;
                sh.p2.sbox[i][2] = bx2; sh.p2.sbox[i][3] = by2;
                sh.p2.sarea[i] = (bx2 - bx1 + 1.f) * (by2 - by1 + 1.f);
            }
            __syncthreads();
            int nwords = ((n + 63) >> 6);
            for (int w = t; w < n * (FASTN/64); w += 256) {
                int i = w >> 2, wb = w & 3;
                if (wb >= nwords || ((wb + 1) << 6) - 1 <= i) { sh.p2.mask[i][wb] = 0ULL; continue; }
                float ax1 = sh.p2.sbox[i][0], ay1 = sh.p2.sbox[i][1];
                float ax2 = sh.p2.sbox[i][2], ay2 = sh.p2.sbox[i][3];
                float aarea = sh.p2.sarea[i];
                unsigned long long bits = 0ULL;
                int jbase = wb << 6;
                #pragma unroll 4
                for (int b = 0; b < 64; ++b) {
                    int j = jbase + b;
                    if (j < n && j > i) {
                        float bx1 = sh.p2.sbox[j][0], by1 = sh.p2.sbox[j][1];
                        float bx2 = sh.p2.sbox[j][2], by2 = sh.p2.sbox[j][3];
                        float xx1 = fmaxf(ax1, bx1), yy1 = fmaxf(ay1, by1);
                        float xx2 = fminf(ax2, bx2), yy2 = fminf(ay2, by2);
                        float iw = fmaxf(xx2 - xx1 + 1.f, 0.f);
                        float ih = fmaxf(yy2 - yy1 + 1.f, 0.f);
                        float inter = iw * ih;
                        if (inter / (aarea + sh.p2.sarea[j] - inter) > NMS_T) bits |= (1ULL << b);
                    }
                }
                sh.p2.mask[i][wb] = bits;
            }
            __syncthreads();
            if (t < 64) {
                int lane = t;
                unsigned long long kb = 0ULL;
                if (lane < 4) {
                    int rem = n - (lane << 6);
                    if (rem >= 64) kb = ~0ULL;
                    else if (rem > 0) kb = (1ULL << rem) - 1ULL;
                }
                unsigned long long rm = 0ULL;
                for (int i = 0; i < n; ++i) {
                    unsigned long long rw = __shfl(rm, i >> 6, 64);
                    if (!((rw >> (i & 63)) & 1ULL)) {
                        unsigned long long mrow = (lane < 4) ? sh.p2.mask[i][lane] : 0ULL;
                        rm |= mrow;
                    }
                }
                if (lane < 4) sh.p2.keepw[lane] = kb & ~rm;
            }
            __syncthreads();
            for (int i = t; i < n; i += 256)
                sh.p2.keep[i] = (int)((sh.p2.keepw[i >> 6] >> (i & 63)) & 1ULL);
            __syncthreads();
        } else {
            for (int i = t; i < n; i += 256) sh.p2.keep[i] = 1;
            __syncthreads();
            for (int i = 0; i < n; ++i) {
                if (sh.p2.keep[i]) {
                    unsigned long long ki = sh.p2.key[i];
                    int mi = NPI - 1 - (int)(ki & 0xFFFFFFFFu);
                    float ax1 = sh.p2.box[mi][0], ay1 = sh.p2.box[mi][1];
                    float ax2 = sh.p2.box[mi][2], ay2 = sh.p2.box[mi][3];
                    float aarea = (ax2 - ax1 + 1.f) * (ay2 - ay1 + 1.f);
                    for (int jj = i + 1 + t; jj < n; jj += 256) {
                        if (sh.p2.keep[jj]) {
                            int mj = NPI - 1 - (int)(sh.p2.key[jj] & 0xFFFFFFFFu);
                            float bx1 = sh.p2.box[mj][0], by1 = sh.p2.box[mj][1];
                            float bx2 = sh.p2.box[mj][2], by2 = sh.p2.box[mj][3];
                            float xx1 = fmaxf(ax1, bx1), yy1 = fmaxf(ay1, by1);
                            float xx2 = fminf(ax2, bx2), yy2 = fminf(ay2, by2);
                            float iw = fmaxf(xx2 - xx1 + 1.f, 0.f);
                            float ih = fmaxf(yy2 - yy1 + 1.f, 0.f);
                            float inter = iw * ih;
                            float barea = (bx2 - bx1 + 1.f) * (by2 - by1 + 1.f);
                            if (inter / (aarea + barea - inter) > NMS_T) sh.p2.keep[jj] = 0;
                        }
                    }
                }
                __syncthreads();
            }
        }
        // parallel compaction
        {
            int lane = t & 63, w = t >> 6;
            int k0 = sh.p2.keep[4 * t], k1 = sh.p2.keep[4 * t + 1];
            int k2 = sh.p2.keep[4 * t + 2], k3 = sh.p2.keep[4 * t + 3];
            unsigned s = (unsigned)(k0 + k1 + k2 + k3);
            unsigned v = s;
            #pragma unroll
            for (int off = 1; off < 64; off <<= 1) {
                unsigned u = __shfl_up(v, off, 64);
                v += (lane >= off) ? u : 0u;
            }
            if (lane == 63) sh.p2.wpre[w] = v;
            __syncthreads();
            unsigned woff = 0;
            for (int w2 = 0; w2 < w; ++w2) woff += sh.p2.wpre[w2];
            unsigned r = v + woff - s;
            #pragma unroll
            for (int j = 0; j < 4; ++j) {
                int i = 4 * t + j;
                int kv = (j == 0) ? k0 : (j == 1) ? k1 : (j == 2) ? k2 : k3;
                if (kv && r < DETS) {
                    unsigned long long ki = sh.p2.key[i];
                    int mi = NPI - 1 - (int)(ki & 0xFFFFFFFFu);
                    int slot = pid * DETS + (int)r;
                    escore[slot] = __uint_as_float((unsigned)(ki >> 32));
                    ekey[slot] = (unsigned)(c * NPI + i);
                    ebox[slot * 4 + 0] = sh.p2.box[mi][0];
                    ebox[slot * 4 + 1] = sh.p2.box[mi][1];
                    ebox[slot * 4 + 2] = sh.p2.box[mi][2];
                    ebox[slot * 4 + 3] = sh.p2.box[mi][3];
                }
                r += (unsigned)kv;
            }
            __syncthreads();
            if (t == 0) {
                unsigned tot = sh.p2.wpre[0] + sh.p2.wpre[1] + sh.p2.wpre[2] + sh.p2.wpre[3];
                gcnt[pid] = (int)(tot < DETS ? tot : DETS);
            }
        }
    }

    // ---- completion protocol: last-done block of this image runs the merge ----
    __threadfence();          // release: make this block's global writes visible
    __syncthreads();
    if (t == 0) lastflag = (atomicAdd(&done[img], 1) == NFG - 1);
    __syncthreads();
    if (lastflag) {
        __threadfence();      // acquire: see all 80 blocks' writes
        merge_image(img, sh.p3, gcnt, escore, ekey, ebox, out);
    }
}

extern "C" void kernel_launch(void* const* d_in, const int* in_sizes, int n_in,
                              void* d_out, int out_size, void* d_ws, size_t ws_size,
                              hipStream_t stream) {
    const float* logits = (const float*)d_in[0];
    const float* boxreg = (const float*)d_in[1];
    const float* props  = (const float*)d_in[2];
    const int*   hptr   = (const int*)d_in[3];
    const int*   wptr   = (const int*)d_in[4];
    float* out = (float*)d_out;
    int M = in_sizes[0] / NCLS; // 8192

    char* ws = (char*)d_ws;
    float*    mx     = (float*)ws;    ws += (size_t)M * sizeof(float);
    float*    den    = (float*)ws;    ws += (size_t)M * sizeof(float);
    int*      done   = (int*)ws;      ws += (size_t)NIMG * sizeof(int) + 32;
    int*      gcnt   = (int*)ws;      ws += (size_t)NIMG * NFG * sizeof(int);
    float*    escore = (float*)ws;    ws += (size_t)NIMG * NCAND * sizeof(float);
    unsigned* ekey   = (unsigned*)ws; ws += (size_t)NIMG * NCAND * sizeof(unsigned);
    float*    ebox   = (float*)ws;    ws += (size_t)NIMG * NCAND * 4 * sizeof(float);

    row_stats<<<M / ROWS, 256, 0, stream>>>(logits, mx, den, done, M);
    nms_merge<<<NIMG * NFG, 256, 0, stream>>>(
        logits, boxreg, props, hptr, wptr, mx, den, done, gcnt,
        escore, ekey, ebox, out, M);
}

// Round 9
// 66.434 us; speedup vs baseline: 2.7505x; 1.5926x over previous
//
#include <hip/hip_runtime.h>
#include <stdint.h>
#include <math.h>

#define NCLS 81
#define NFG  80
#define NPI  1024
#define NIMG 8
#define DETS 100
#define SCORE_T 0.05f
#define NMS_T   0.5f
#define NCAND   (NFG * DETS)   // 8000
#define CAND_CAP 1024
#define FASTN 256              // block bitmask-NMS path limit
#define ROWS 64                // rows per softmax block

static constexpr float BBOX_CLIP = 4.1351665567423557f; // log(1000/16)

// ---------------- Kernel 1: softmax -> transposed prob matrix (R5, proven) ----
__global__ __launch_bounds__(256) void softmax_probT(
    const float* __restrict__ logits, float* __restrict__ probT, int M)
{
    __shared__ float tile[ROWS * NCLS];
    __shared__ float mx[ROWS], dn[ROWS];
    int t = threadIdx.x;
    int rbase = blockIdx.x * ROWS;
    for (int idx = t; idx < ROWS * NCLS; idx += 256)
        tile[idx] = logits[(size_t)rbase * NCLS + idx];
    __syncthreads();
    if (t < ROWS) {
        const float* r = tile + t * NCLS;
        float m = r[0];
        #pragma unroll
        for (int j = 1; j < NCLS; ++j) m = fmaxf(m, r[j]);
        float s = 0.f;
        #pragma unroll
        for (int j = 0; j < NCLS; ++j) s += expf(r[j] - m);
        mx[t] = m; dn[t] = s;
    }
    __syncthreads();
    for (int o = t; o < ROWS * NFG; o += 256) {
        int r = o & 63;
        int c = o >> 6;
        probT[(size_t)c * M + rbase + r] = expf(tile[r * NCLS + (c + 1)] - mx[r]) / dn[r];
    }
}

// ---------------- Kernel 2: per-(image,class) NMS, rank-order sort ----------------
struct ShP2 {
    float box[NPI][4];                         // 16KB (by proposal id)
    unsigned long long key[NPI];               // 8KB (append order)
    unsigned long long skey[NPI];              // 8KB (sorted)
    int keep[NPI];                             // 4KB
    float sbox[FASTN][4];                      // 4KB
    float sarea[FASTN];                        // 1KB
    unsigned long long mask[FASTN][FASTN/64];  // 8KB
    unsigned long long keepw[FASTN/64];
    unsigned wpre[4];
};

__global__ __launch_bounds__(256) void per_class_nms(
    const float* __restrict__ probT, const float* __restrict__ boxreg,
    const float* __restrict__ props, const int* __restrict__ hptr,
    const int* __restrict__ wptr, int* __restrict__ out_cnt,
    float* __restrict__ out_score, unsigned* __restrict__ out_key,
    float* __restrict__ out_box, int M)
{
    int pid = blockIdx.x;           // 0..639
    int img = pid / NFG;
    int c   = pid % NFG;
    int cls = c + 1;

    __shared__ ShP2 sp;
    __shared__ int cnt;
    int t = threadIdx.x;
    float W1 = (float)(*wptr - 1);
    float H1 = (float)(*hptr - 1);

    if (t == 0) cnt = 0;
    __syncthreads();

    // ---- load phase: coalesced float4 prob read, decode passing proposals ----
    {
        const float4 pv = *(const float4*)(probT + (size_t)c * M + img * NPI + 4 * t);
        float pr[4] = {pv.x, pv.y, pv.z, pv.w};
        #pragma unroll
        for (int j = 0; j < 4; ++j) {
            if (pr[j] > SCORE_T) {
                int m = 4 * t + j;
                int g = img * NPI + m;
                const float4 pb = *(const float4*)(props + (size_t)g * 4);
                float x1 = pb.x, y1 = pb.y, x2 = pb.z, y2 = pb.w;
                float w  = x2 - x1 + 1.0f, h = y2 - y1 + 1.0f;
                float cx = x1 + 0.5f * w,  cy = y1 + 0.5f * h;
                const float4 rc = *(const float4*)(boxreg + (size_t)g * (4 * NCLS) + 4 * cls);
                float dx = rc.x / 10.0f, dy = rc.y / 10.0f;
                float dw = fminf(rc.z / 5.0f, BBOX_CLIP);
                float dh = fminf(rc.w / 5.0f, BBOX_CLIP);
                float pcx = dx * w + cx, pcy = dy * h + cy;
                float pw = expf(dw) * w, ph = expf(dh) * h;
                float bx1 = fminf(fmaxf(pcx - 0.5f * pw, 0.f), W1);
                float by1 = fminf(fmaxf(pcy - 0.5f * ph, 0.f), H1);
                float bx2 = fminf(fmaxf(pcx + 0.5f * pw - 1.0f, 0.f), W1);
                float by2 = fminf(fmaxf(pcy + 0.5f * ph - 1.0f, 0.f), H1);
                sp.box[m][0] = bx1; sp.box[m][1] = by1;
                sp.box[m][2] = bx2; sp.box[m][3] = by2;
                int p = atomicAdd(&cnt, 1);
                sp.key[p] = ((unsigned long long)__float_as_uint(pr[j]) << 32)
                          | (unsigned)(NPI - 1 - m);
            }
        }
    }
    __syncthreads();
    int n = cnt;

    if (n <= 64) {
        // ---- wave fast path (no further barriers) ----
        if (t < 64) {
            int lane = t;
            unsigned long long k = (lane < n) ? sp.key[lane] : 0ULL;
            #pragma unroll
            for (int kk = 2; kk <= 64; kk <<= 1) {
                #pragma unroll
                for (int j = kk >> 1; j > 0; j >>= 1) {
                    unsigned long long o = __shfl_xor(k, j, 64);
                    bool take_max = (((lane & kk) == 0) == ((lane & j) == 0));
                    k = take_max ? (k > o ? k : o) : (k < o ? k : o);
                }
            }
            bool valid = (lane < n);
            float bx1 = 0.f, by1 = 0.f, bx2 = 0.f, by2 = 0.f, area = 0.f;
            if (valid) {
                int mi = NPI - 1 - (int)(k & 0xFFFFFFFFu);
                bx1 = sp.box[mi][0]; by1 = sp.box[mi][1];
                bx2 = sp.box[mi][2]; by2 = sp.box[mi][3];
                area = (bx2 - bx1 + 1.f) * (by2 - by1 + 1.f);
            }
            unsigned long long sup = 0ULL;
            for (int i = 0; i < n; ++i) {
                bool alive = !((sup >> i) & 1ULL);
                float ax1 = __shfl(bx1, i, 64), ay1 = __shfl(by1, i, 64);
                float ax2 = __shfl(bx2, i, 64), ay2 = __shfl(by2, i, 64);
                float aarea = __shfl(area, i, 64);
                bool s = false;
                if (alive && valid && lane > i) {
                    float xx1 = fmaxf(ax1, bx1), yy1 = fmaxf(ay1, by1);
                    float xx2 = fminf(ax2, bx2), yy2 = fminf(ay2, by2);
                    float iw = fmaxf(xx2 - xx1 + 1.f, 0.f);
                    float ih = fmaxf(yy2 - yy1 + 1.f, 0.f);
                    float inter = iw * ih;
                    s = inter / (aarea + area - inter) > NMS_T;
                }
                sup |= __ballot(s);
            }
            bool kept = valid && !((sup >> lane) & 1ULL);
            unsigned long long keptm = __ballot(kept);
            int rank = __popcll(keptm & ((1ULL << lane) - 1ULL));
            if (kept && rank < DETS) {
                int slot = pid * DETS + rank;
                out_score[slot] = __uint_as_float((unsigned)(k >> 32));
                out_key[slot] = (unsigned)(c * NPI + lane);
                out_box[slot * 4 + 0] = bx1; out_box[slot * 4 + 1] = by1;
                out_box[slot * 4 + 2] = bx2; out_box[slot * 4 + 3] = by2;
            }
            if (lane == 0) {
                int tot = __popcll(keptm);
                out_cnt[pid] = tot < DETS ? tot : DETS;
            }
        }
        return;
    }

    // ---- rank-order sort: skey[rank] = key (keys unique, 1 barrier) ----
    // inner loop is an LDS broadcast (all threads read same key[j] sequence)
    for (int i = t; i < NPI; i += 256) sp.keep[i] = 0;   // zero keep alongside
    for (int i = t; i < n; i += 256) {
        unsigned long long ki = sp.key[i];
        int r = 0;
        for (int j = 0; j < n; ++j) r += (sp.key[j] > ki) ? 1 : 0;
        sp.skey[r] = ki;
    }
    __syncthreads();

    if (n <= FASTN) {
        // ---------- bitmask NMS on sorted order ----------
        for (int i = t; i < n; i += 256) {
            int mi = NPI - 1 - (int)(sp.skey[i] & 0xFFFFFFFFu);
            float bx1 = sp.box[mi][0], by1 = sp.box[mi][1];
            float bx2 = sp.box[mi][2], by2 = sp.box[mi][3];
            sp.sbox[i][0] = bx1; sp.sbox[i][1] = by1;
            sp.sbox[i][2] = bx2; sp.sbox[i][3] = by2;
            sp.sarea[i] = (bx2 - bx1 + 1.f) * (by2 - by1 + 1.f);
        }
        __syncthreads();
        int nwords = ((n + 63) >> 6);
        for (int w = t; w < n * (FASTN/64); w += 256) {
            int i = w >> 2, wb = w & 3;
            if (wb >= nwords || ((wb + 1) << 6) - 1 <= i) { sp.mask[i][wb] = 0ULL; continue; }
            float ax1 = sp.sbox[i][0], ay1 = sp.sbox[i][1];
            float ax2 = sp.sbox[i][2], ay2 = sp.sbox[i][3];
            float aarea = sp.sarea[i];
            unsigned long long bits = 0ULL;
            int jbase = wb << 6;
            #pragma unroll 4
            for (int b = 0; b < 64; ++b) {
                int j = jbase + b;
                if (j < n && j > i) {
                    float bx1 = sp.sbox[j][0], by1 = sp.sbox[j][1];
                    float bx2 = sp.sbox[j][2], by2 = sp.sbox[j][3];
                    float xx1 = fmaxf(ax1, bx1), yy1 = fmaxf(ay1, by1);
                    float xx2 = fminf(ax2, bx2), yy2 = fminf(ay2, by2);
                    float iw = fmaxf(xx2 - xx1 + 1.f, 0.f);
                    float ih = fmaxf(yy2 - yy1 + 1.f, 0.f);
                    float inter = iw * ih;
                    if (inter / (aarea + sp.sarea[j] - inter) > NMS_T) bits |= (1ULL << b);
                }
            }
            sp.mask[i][wb] = bits;
        }
        __syncthreads();
        if (t < 64) {
            int lane = t;
            unsigned long long kb = 0ULL;
            if (lane < 4) {
                int rem = n - (lane << 6);
                if (rem >= 64) kb = ~0ULL;
                else if (rem > 0) kb = (1ULL << rem) - 1ULL;
            }
            unsigned long long rm = 0ULL;
            for (int i = 0; i < n; ++i) {
                unsigned long long rw = __shfl(rm, i >> 6, 64);
                if (!((rw >> (i & 63)) & 1ULL)) {
                    unsigned long long mrow = (lane < 4) ? sp.mask[i][lane] : 0ULL;
                    rm |= mrow;
                }
            }
            if (lane < 4) sp.keepw[lane] = kb & ~rm;
        }
        __syncthreads();
        for (int i = t; i < n; i += 256)
            sp.keep[i] = (int)((sp.keepw[i >> 6] >> (i & 63)) & 1ULL);
        __syncthreads();
    } else {
        // ---------- serial greedy on sorted order (rare) ----------
        for (int i = t; i < n; i += 256) sp.keep[i] = 1;
        __syncthreads();
        for (int i = 0; i < n; ++i) {
            if (sp.keep[i]) {
                unsigned long long ki = sp.skey[i];
                int mi = NPI - 1 - (int)(ki & 0xFFFFFFFFu);
                float ax1 = sp.box[mi][0], ay1 = sp.box[mi][1];
                float ax2 = sp.box[mi][2], ay2 = sp.box[mi][3];
                float aarea = (ax2 - ax1 + 1.f) * (ay2 - ay1 + 1.f);
                for (int jj = i + 1 + t; jj < n; jj += 256) {
                    if (sp.keep[jj]) {
                        int mj = NPI - 1 - (int)(sp.skey[jj] & 0xFFFFFFFFu);
                        float bx1 = sp.box[mj][0], by1 = sp.box[mj][1];
                        float bx2 = sp.box[mj][2], by2 = sp.box[mj][3];
                        float xx1 = fmaxf(ax1, bx1), yy1 = fmaxf(ay1, by1);
                        float xx2 = fminf(ax2, bx2), yy2 = fminf(ay2, by2);
                        float iw = fmaxf(xx2 - xx1 + 1.f, 0.f);
                        float ih = fmaxf(yy2 - yy1 + 1.f, 0.f);
                        float inter = iw * ih;
                        float barea = (bx2 - bx1 + 1.f) * (by2 - by1 + 1.f);
                        if (inter / (aarea + barea - inter) > NMS_T) sp.keep[jj] = 0;
                    }
                }
            }
            __syncthreads();
        }
    }

    // ---------- parallel compaction via block prefix scan ----------
    {
        int lane = t & 63, w = t >> 6;
        int k0 = sp.keep[4 * t], k1 = sp.keep[4 * t + 1];
        int k2 = sp.keep[4 * t + 2], k3 = sp.keep[4 * t + 3];
        unsigned s = (unsigned)(k0 + k1 + k2 + k3);
        unsigned v = s;
        #pragma unroll
        for (int off = 1; off < 64; off <<= 1) {
            unsigned u = __shfl_up(v, off, 64);
            v += (lane >= off) ? u : 0u;
        }
        if (lane == 63) sp.wpre[w] = v;
        __syncthreads();
        unsigned woff = 0;
        for (int w2 = 0; w2 < w; ++w2) woff += sp.wpre[w2];
        unsigned r = v + woff - s;
        #pragma unroll
        for (int j = 0; j < 4; ++j) {
            int i = 4 * t + j;
            int kv = (j == 0) ? k0 : (j == 1) ? k1 : (j == 2) ? k2 : k3;
            if (kv && r < DETS) {
                unsigned long long ki = sp.skey[i];
                int mi = NPI - 1 - (int)(ki & 0xFFFFFFFFu);
                int slot = pid * DETS + (int)r;
                out_score[slot] = __uint_as_float((unsigned)(ki >> 32));
                out_key[slot] = (unsigned)(c * NPI + i);
                out_box[slot * 4 + 0] = sp.box[mi][0];
                out_box[slot * 4 + 1] = sp.box[mi][1];
                out_box[slot * 4 + 2] = sp.box[mi][2];
                out_box[slot * 4 + 3] = sp.box[mi][3];
            }
            r += (unsigned)kv;
        }
        __syncthreads();
        if (t == 0) {
            unsigned tot = sp.wpre[0] + sp.wpre[1] + sp.wpre[2] + sp.wpre[3];
            out_cnt[pid] = (int)(tot < DETS ? tot : DETS);
        }
    }
}

// ---------------- Kernel 3: per-image top-100, radix-select + rank write ----------
__device__ __forceinline__ void suffix_select256(
    unsigned* hist, unsigned* wtot, int K, int* outB, unsigned* outAbove)
{
    int t = threadIdx.x, lane = t & 63, w = t >> 6;
    unsigned loc[16]; unsigned ps = 0;
    #pragma unroll
    for (int j = 0; j < 16; ++j) { loc[j] = hist[t * 16 + j]; ps += loc[j]; }
    unsigned v = ps;
    #pragma unroll
    for (int off = 1; off < 64; off <<= 1) {
        unsigned u = __shfl_down(v, off, 64);
        v += (lane + off < 64) ? u : 0u;
    }
    if (lane == 0) wtot[w] = v;
    __syncthreads();
    unsigned woff = 0;
    for (int w2 = w + 1; w2 < 4; ++w2) woff += wtot[w2];
    unsigned base = v + woff - ps;
    unsigned suf = 0;
    #pragma unroll
    for (int j = 15; j >= 0; --j) {
        unsigned A = base + suf;
        if ((int)A < K && (int)(A + loc[j]) >= K) { *outB = t * 16 + j; *outAbove = A; }
        suf += loc[j];
    }
    __syncthreads();
}

__global__ __launch_bounds__(256) void topk_merge(
    const int* __restrict__ cnts, const float* __restrict__ escore,
    const unsigned* __restrict__ ekey, const float* __restrict__ ebox,
    float* __restrict__ out)
{
    int img = blockIdx.x;
    __shared__ unsigned sc[NCAND];                 // 32000B score-bit cache
    __shared__ unsigned hist[4096];                // 16KB
    __shared__ unsigned long long cand[CAND_CAP];  // 8KB
    __shared__ int scnts[NFG];
    __shared__ unsigned wtot[4];
    __shared__ int sB1, sB2, sNc;
    __shared__ unsigned sAb1, sAb2;

    int t = threadIdx.x;
    if (t < NFG) scnts[t] = cnts[img * NFG + t];
    if (t == 0) { sB1 = 0; sB2 = 0; sNc = 0; sAb1 = 0; sAb2 = 0; }
    for (int i = t; i < 4096; i += 256) hist[i] = 0;
    __syncthreads();

    // load + cache score bits (coalesced), build L1 histogram [30:19]
    for (int p = t; p < NCAND; p += 256) {
        unsigned fb = 0;
        if ((p % DETS) < scnts[p / DETS]) fb = __float_as_uint(escore[img * NCAND + p]);
        sc[p] = fb;
        if (fb) atomicAdd(&hist[fb >> 19], 1u);
    }
    __syncthreads();
    suffix_select256(hist, wtot, DETS, &sB1, &sAb1);
    int B1 = sB1; unsigned ab1 = sAb1;

    for (int i = t; i < 4096; i += 256) hist[i] = 0;
    __syncthreads();
    for (int p = t; p < NCAND; p += 256) {
        unsigned fb = sc[p];
        if (fb && (int)(fb >> 19) == B1) atomicAdd(&hist[(fb >> 7) & 0xFFFu], 1u);
    }
    __syncthreads();
    suffix_select256(hist, wtot, DETS - (int)ab1, &sB2, &sAb2);
    int B2 = sB2;

    // compact candidates with full tie-break keys
    for (int p = t; p < NCAND; p += 256) {
        unsigned fb = sc[p];
        if (fb) {
            int d1 = (int)(fb >> 19);
            bool ok = d1 > B1 || (d1 == B1 && (int)((fb >> 7) & 0xFFFu) >= B2);
            if (ok) {
                int pos = atomicAdd(&sNc, 1);
                if (pos < CAND_CAP) {
                    unsigned fk = ekey[img * NCAND + p];
                    cand[pos] = ((unsigned long long)fb << 32)
                              | (((0x1FFFFu - fk) << 13) | (unsigned)p);
                }
            }
        }
    }
    __syncthreads();
    int nc = sNc < CAND_CAP ? sNc : CAND_CAP;

    float* oScore = out;
    float* oBox   = out + NIMG * DETS;
    float* oLab   = out + NIMG * DETS * 5;

    // zero-fill output slots that no candidate will write (rank >= nc)
    for (int k = t; k < DETS; k += 256) {
        if (k >= nc) {
            int o = img * DETS + k;
            oScore[o] = 0.f;
            oBox[o * 4 + 0] = 0.f; oBox[o * 4 + 1] = 0.f;
            oBox[o * 4 + 2] = 0.f; oBox[o * 4 + 3] = 0.f;
            oLab[o] = 0.f;
        }
    }

    // rank-order direct write: rank = #{cand > mine}; unique keys
    for (int i = t; i < nc; i += 256) {
        unsigned long long ki = cand[i];
        int r = 0;
        for (int j = 0; j < nc; ++j) r += (cand[j] > ki) ? 1 : 0;
        if (r < DETS) {
            float scv = __uint_as_float((unsigned)(ki >> 32));
            unsigned low = (unsigned)(ki & 0xFFFFFFFFu);
            unsigned flatkey = 0x1FFFFu - ((low >> 13) & 0x1FFFFu);
            int p = (int)(low & 0x1FFFu);
            int gp = img * NCAND + p;
            int o = img * DETS + r;
            oScore[o] = scv;
            oBox[o * 4 + 0] = ebox[gp * 4 + 0];
            oBox[o * 4 + 1] = ebox[gp * 4 + 1];
            oBox[o * 4 + 2] = ebox[gp * 4 + 2];
            oBox[o * 4 + 3] = ebox[gp * 4 + 3];
            oLab[o] = (float)((flatkey >> 10) + 1);
        }
    }
}

extern "C" void kernel_launch(void* const* d_in, const int* in_sizes, int n_in,
                              void* d_out, int out_size, void* d_ws, size_t ws_size,
                              hipStream_t stream) {
    const float* logits = (const float*)d_in[0];
    const float* boxreg = (const float*)d_in[1];
    const float* props  = (const float*)d_in[2];
    const int*   hptr   = (const int*)d_in[3];
    const int*   wptr   = (const int*)d_in[4];
    float* out = (float*)d_out;
    int M = in_sizes[0] / NCLS; // 8192

    char* ws = (char*)d_ws;
    float*    probT  = (float*)ws;    ws += (size_t)NFG * M * sizeof(float);
    int*      gcnt   = (int*)ws;      ws += (size_t)NIMG * NFG * sizeof(int);
    float*    escore = (float*)ws;    ws += (size_t)NIMG * NCAND * sizeof(float);
    unsigned* ekey   = (unsigned*)ws; ws += (size_t)NIMG * NCAND * sizeof(unsigned);
    float*    ebox   = (float*)ws;    ws += (size_t)NIMG * NCAND * 4 * sizeof(float);

    softmax_probT<<<M / ROWS, 256, 0, stream>>>(logits, probT, M);
    per_class_nms<<<NIMG * NFG, 256, 0, stream>>>(
        probT, boxreg, props, hptr, wptr, gcnt, escore, ekey, ebox, M);
    topk_merge<<<NIMG, 256, 0, stream>>>(gcnt, escore, ekey, ebox, out);
}